// Round 9
// baseline (84.131 us; speedup 1.0000x reference)
//
#include <hip/hip_runtime.h>
#include <hip/hip_bf16.h>
#include <math.h>

#define D 300
#define R 5
#define NE 1000000
#define B 32
#define NG 25000
#define NS 25000
#define NROWS 50000
#define NT16 3125      // 16-row j-tiles (50000 = 3125*16 exactly)
#define NW 6250        // waves = NT16 * 2 b-halves

typedef __bf16 bf16x8 __attribute__((ext_vector_type(8)));
typedef float f32x4 __attribute__((ext_vector_type(4)));

// ws layout (floats):
//   wsum [0, 48000)   wcnt [48000, 48160)   hcf [48160, 57760)
//   done int at 57760, pad to 57764
//   hcb  bf16 [32][320] at float-offset 57764 -> [57764, 62884)
//   pm2  float2 [64][3125] at 62884 -> [62884, 462884)
//   lse  [462884, 462948)

__device__ __forceinline__ void online_upd(float& m, float& s, float v) {
    if (v > m) { s = s * __expf(m - v) + 1.0f; m = v; }
    else       { s += __expf(v - m); }
}
__device__ __forceinline__ void online_merge(float& m, float& s, float om, float os) {
    float M = fmaxf(m, om);
    s = s * __expf(m - M) + os * __expf(om - M);
    m = M;
}

__global__ void zero_ws(float4* __restrict__ p) {
    int i = blockIdx.x * 256 + threadIdx.x;
    if (i < 14441) p[i] = float4{0.f, 0.f, 0.f, 0.f};  // wsum|wcnt|hcf|done
}

// Fused scan + accumulate (proven): bloom dst, compact to LDS, coalesced row-adds.
__global__ __launch_bounds__(256) void scan_accum(
        const int* __restrict__ ei, const int* __restrict__ et,
        const int* __restrict__ cur, const float* __restrict__ x,
        float* __restrict__ wsum, float* __restrict__ wcnt) {
    __shared__ unsigned int tbl[32];
    __shared__ int curl[B];
    __shared__ int lcnt;
    __shared__ int2 loc[64];
    int tid = threadIdx.x;
    if (tid < 32) tbl[tid] = 0u;
    if (tid == 0) lcnt = 0;
    __syncthreads();
    if (tid < B) { int c = cur[tid]; curl[tid] = c; atomicOr(&tbl[(c >> 5) & 31], 1u << (c & 31)); }
    __syncthreads();
    long base = ((long)blockIdx.x * 256 + tid) * 4;
    if (base < NE) {
        int ds4[4];
        if (base + 4 <= NE) {
            int4 d4 = *(const int4*)(ei + NE + base);
            ds4[0] = d4.x; ds4[1] = d4.y; ds4[2] = d4.z; ds4[3] = d4.w;
        } else {
            for (int k = 0; k < 4; ++k) ds4[k] = (base + k < NE) ? ei[NE + base + k] : -1;
        }
        #pragma unroll
        for (int k = 0; k < 4; ++k) {
            int dst = ds4[k];
            if (dst < 0) continue;
            if (!(tbl[(dst >> 5) & 31] & (1u << (dst & 31)))) continue;
            int e = (int)base + k;
            int r = -1, src = 0;
            for (int b = 0; b < B; ++b) {
                if (dst == curl[b]) {
                    if (r < 0) { r = et[e]; src = ei[e]; }
                    atomicAdd(&wcnt[b * R + r], 1.0f);
                    int p = atomicAdd(&lcnt, 1);
                    if (p < 64) loc[p] = int2{src, b * R + r};
                }
            }
        }
    }
    __syncthreads();
    int n = lcnt; if (n > 64) n = 64;
    for (int m = 0; m < n; ++m) {
        int2 pr = loc[m];
        const float* xs = x + (long)pr.x * D;
        float* sm = wsum + (long)pr.y * D;
        for (int t = tid; t < D; t += 256) atomicAdd(&sm[t], xs[t]);
    }
}

// RGCN transform: 72 blocks x 25-row K-chunks; last block emits hcb bf16 [32][320].
__global__ __launch_bounds__(320) void rgcn_hc(
        const float* __restrict__ x, const int* __restrict__ cur,
        const float* __restrict__ comp, const float* __restrict__ root,
        const float* __restrict__ basis, const float* __restrict__ bias,
        const float* __restrict__ wsum, const float* __restrict__ wcnt,
        float* __restrict__ hcf, int* __restrict__ done, __bf16* __restrict__ hcb) {
    int kc = blockIdx.x, t = threadIdx.x;
    __shared__ float uL[800];       // 32 b x 25 k
    __shared__ float inv[B * R];
    __shared__ float cmp[R * R];
    __shared__ int lastFlag;
    if (t < B * R) inv[t] = 1.0f / fmaxf(wcnt[t], 1.0f);
    if (t >= 160 && t < 160 + R * R) cmp[t - 160] = comp[t - 160];
    __syncthreads();
    int d0 = kc * 25;
    if (d0 < 300) {
        for (int i = t; i < 800; i += 320) {
            int b = i / 25, dd = i - b * 25;
            uL[i] = x[(long)cur[b] * D + d0 + dd];
        }
    } else {
        int g0 = d0 - 300;
        int bb = g0 / 300, t0 = g0 - bb * 300;   // 25 | 300, no straddle
        for (int i = t; i < 800; i += 320) {
            int b = i / 25, dd = i - b * 25;
            float a = 0.f;
            #pragma unroll
            for (int r = 0; r < R; ++r)
                a = fmaf(cmp[r * R + bb] * inv[b * R + r], wsum[(long)(b * R + r) * D + t0 + dd], a);
            uL[i] = a;
        }
    }
    __syncthreads();
    if (t < D) {
        const float* Mb = (d0 < 300) ? (root + (long)d0 * D) : (basis + (long)(d0 - 300) * D);
        float acc[B] = {};
        #pragma unroll 5
        for (int i = 0; i < 25; ++i) {
            float m = Mb[(long)i * D + t];
            #pragma unroll
            for (int b = 0; b < B; ++b) acc[b] = fmaf(uL[b * 25 + i], m, acc[b]);
        }
        for (int b = 0; b < B; ++b) atomicAdd(&hcf[b * D + t], acc[b]);
    }
    __syncthreads();
    if (t == 0) {
        __threadfence();
        int p = atomicAdd(done, 1);
        lastFlag = (p == 71);
    }
    __syncthreads();
    if (!lastFlag) return;
    __threadfence();
    for (int i = t; i < 32 * 320; i += 320) {
        int b = i / 320, kk = i - b * 320;
        float a = 0.f;
        if (kk < D) a = fmaxf(atomicAdd(&hcf[b * D + kk], 0.0f) + bias[kk], 0.f);
        hcb[i] = (__bf16)a;
    }
}

// Head GEMM, 16x16x32 MFMA. ONE WAVE PER BLOCK (64 thr, no min-waves cap ->
// no VGPR spill; bfrag[10]=40 VGPR register-resident). 6250 blocks ~ 24 waves/CU.
__global__ __launch_bounds__(64) void head_gemm16(
    const __bf16* __restrict__ hcb, const float* __restrict__ wg, const float* __restrict__ bg,
    const float* __restrict__ wsn, const float* __restrict__ bsn,
    float* __restrict__ out, float2* __restrict__ pm2) {
    int l = threadIdx.x;
    int gw = blockIdx.x;
    int jt = gw >> 1, bh = gw & 1;
    int j0 = jt * 16;
    int ln = l & 15, og = l >> 4;          // j/b-in-tile, k-octet (0..3)
    int b = bh * 16 + ln;

    bf16x8 bfrag[10];
    const __bf16* hrow = hcb + b * 320 + og * 8;
    #pragma unroll
    for (int s = 0; s < 10; ++s) bfrag[s] = *(const bf16x8*)(hrow + 32 * s);

    int row = j0 + ln;
    const float* wrow = ((row < NG) ? (wg + (long)row * D) : (wsn + (long)(row - NG) * D)) + og * 8;

    f32x4 acc = {};
    #pragma unroll
    for (int s = 0; s < 9; ++s) {
        float4 w0 = *(const float4*)(wrow + 32 * s);
        float4 w1 = *(const float4*)(wrow + 32 * s + 4);
        bf16x8 a;
        a[0]=(__bf16)w0.x; a[1]=(__bf16)w0.y; a[2]=(__bf16)w0.z; a[3]=(__bf16)w0.w;
        a[4]=(__bf16)w1.x; a[5]=(__bf16)w1.y; a[6]=(__bf16)w1.z; a[7]=(__bf16)w1.w;
        acc = __builtin_amdgcn_mfma_f32_16x16x32_bf16(a, bfrag[s], acc, 0, 0, 0);
    }
    {   // tail: k = 288 + og*8 + t; og0: 288..295, og1: 296..299(+pad), og2/3: pad
        float4 w0 = float4{0.f,0.f,0.f,0.f}, w1 = float4{0.f,0.f,0.f,0.f};
        if (og == 0) { w0 = *(const float4*)(wrow + 288); w1 = *(const float4*)(wrow + 292); }
        else if (og == 1) { w0 = *(const float4*)(wrow + 288); }  // k 296..299
        bf16x8 a;
        a[0]=(__bf16)w0.x; a[1]=(__bf16)w0.y; a[2]=(__bf16)w0.z; a[3]=(__bf16)w0.w;
        a[4]=(__bf16)w1.x; a[5]=(__bf16)w1.y; a[6]=(__bf16)w1.z; a[7]=(__bf16)w1.w;
        acc = __builtin_amdgcn_mfma_f32_16x16x32_bf16(a, bfrag[9], acc, 0, 0, 0);
    }

    // C: col = ln (b), row = og*4 + r   (verified R8: absmax unchanged)
    float m0 = -3.0e38f, s0 = 0.f, m1 = -3.0e38f, s1 = 0.f;
    #pragma unroll
    for (int r = 0; r < 4; ++r) {
        int j = j0 + og * 4 + r;
        float bv = (j < NG) ? bg[j] : bsn[j - NG];
        float v = acc[r] + bv;
        float* op = (j < NG) ? (out + (long)b * NG + j)
                             : (out + (long)B * NG + (long)b * NS + (j - NG));
        *op = v;
        if (j < NG) online_upd(m0, s0, v); else online_upd(m1, s1, v);
    }
    #pragma unroll
    for (int o = 16; o <= 32; o <<= 1) {
        float om0 = __shfl_xor(m0, o), os0 = __shfl_xor(s0, o);
        float om1 = __shfl_xor(m1, o), os1 = __shfl_xor(s1, o);
        online_merge(m0, s0, om0, os0);
        online_merge(m1, s1, om1, os1);
    }
    if (og == 0) {
        pm2[(long)b * NT16 + jt]       = float2{m0, s0};
        pm2[(long)(B + b) * NT16 + jt] = float2{m1, s1};
    }
}

// One block per output row: reduce its 3125-tile strip -> lse[row].
__global__ __launch_bounds__(256) void lse_red(const float2* __restrict__ pm2,
                                               float* __restrict__ lse) {
    int rw = blockIdx.x, tid = threadIdx.x;
    const float2* pr = pm2 + (long)rw * NT16;
    float m = -3.0e38f, s = 0.f;
    for (int i = tid; i < NT16; i += 256) { float2 e = pr[i]; online_merge(m, s, e.x, e.y); }
    #pragma unroll
    for (int o = 32; o; o >>= 1) {
        float om = __shfl_xor(m, o), os = __shfl_xor(s, o);
        online_merge(m, s, om, os);
    }
    __shared__ float sm[4], ss[4];
    if ((tid & 63) == 0) { sm[tid >> 6] = m; ss[tid >> 6] = s; }
    __syncthreads();
    if (tid == 0) {
        float M = sm[0], S = ss[0];
        for (int w = 1; w < 4; ++w) online_merge(M, S, sm[w], ss[w]);
        lse[rw] = M + __logf(S);
    }
}

// 1600 blocks: subtract lse over 250-float4 chunks.
__global__ __launch_bounds__(256) void sub_lse(float* __restrict__ out,
                                               const float* __restrict__ lse) {
    int rw = blockIdx.x / 25, c = blockIdx.x % 25;
    float l = lse[rw];
    float4* o4 = (float4*)out + (long)rw * 6250 + c * 250;
    int tid = threadIdx.x;
    if (tid < 250) { float4 v = o4[tid]; v.x -= l; v.y -= l; v.z -= l; v.w -= l; o4[tid] = v; }
}

extern "C" void kernel_launch(void* const* d_in, const int* in_sizes, int n_in,
                              void* d_out, int out_size, void* d_ws, size_t ws_size,
                              hipStream_t stream) {
    const float* x     = (const float*)d_in[0];
    const int*   ei    = (const int*)d_in[1];
    const int*   et    = (const int*)d_in[2];
    const int*   cur   = (const int*)d_in[3];
    const float* basis = (const float*)d_in[4];
    const float* comp  = (const float*)d_in[5];
    const float* root  = (const float*)d_in[6];
    const float* bias  = (const float*)d_in[7];
    const float* wg    = (const float*)d_in[8];
    const float* bgl   = (const float*)d_in[9];
    const float* wsn   = (const float*)d_in[10];
    const float* bsn   = (const float*)d_in[11];
    float* out  = (float*)d_out;
    float* wsf  = (float*)d_ws;
    float*  wsum = wsf;                        // [0, 48000)
    float*  wcnt = wsf + 48000;                // [48000, 48160)
    float*  hcf  = wsf + 48160;                // [48160, 57760)
    int*    done = (int*)(wsf + 57760);
    __bf16* hcb  = (__bf16*)(wsf + 57764);     // 32 x 320 bf16
    float2* pm2  = (float2*)(wsf + 62884);     // 64 x 3125
    float*  lse  = wsf + 462884;               // 64

    zero_ws<<<57, 256, 0, stream>>>((float4*)d_ws);
    scan_accum<<<977, 256, 0, stream>>>(ei, et, cur, x, wsum, wcnt);
    rgcn_hc<<<72, 320, 0, stream>>>(x, cur, comp, root, basis, bias, wsum, wcnt, hcf, done, hcb);
    head_gemm16<<<NW, 64, 0, stream>>>(hcb, wg, bgl, wsn, bsn, out, pm2);
    lse_red<<<64, 256, 0, stream>>>(pm2, lse);
    sub_lse<<<1600, 256, 0, stream>>>(out, lse);
}

// Round 10
// 80.287 us; speedup vs baseline: 1.0479x; 1.0479x over previous
//
#include <hip/hip_runtime.h>
#include <hip/hip_bf16.h>
#include <math.h>

#define D 300
#define R 5
#define NE 1000000
#define B 32
#define NG 25000
#define NS 25000
#define NROWS 50000
#define NT16 3125      // 16-row j-tiles (50000 = 3125*16 exactly)

typedef __bf16 bf16x8 __attribute__((ext_vector_type(8)));
typedef float f32x4 __attribute__((ext_vector_type(4)));

// ws layout (floats):
//   wsum [0, 48000)   wcnt [48000, 48160)   hcf [48160, 57760)
//   done int at 57760, pad to 57764
//   hcb  bf16 [32][320] at float-offset 57764 -> [57764, 62884)
//   pm2  float2 [64][3125] at 62884 -> [62884, 462884)
//   lse  [462884, 462948)

__device__ __forceinline__ void online_upd(float& m, float& s, float v) {
    if (v > m) { s = s * __expf(m - v) + 1.0f; m = v; }
    else       { s += __expf(v - m); }
}
__device__ __forceinline__ void online_merge(float& m, float& s, float om, float os) {
    float M = fmaxf(m, om);
    s = s * __expf(m - M) + os * __expf(om - M);
    m = M;
}

__global__ void zero_ws(float4* __restrict__ p) {
    int i = blockIdx.x * 256 + threadIdx.x;
    if (i < 14441) p[i] = float4{0.f, 0.f, 0.f, 0.f};  // wsum|wcnt|hcf|done
}

// Fused scan + accumulate (proven): bloom dst, compact to LDS, coalesced row-adds.
__global__ __launch_bounds__(256) void scan_accum(
        const int* __restrict__ ei, const int* __restrict__ et,
        const int* __restrict__ cur, const float* __restrict__ x,
        float* __restrict__ wsum, float* __restrict__ wcnt) {
    __shared__ unsigned int tbl[32];
    __shared__ int curl[B];
    __shared__ int lcnt;
    __shared__ int2 loc[64];
    int tid = threadIdx.x;
    if (tid < 32) tbl[tid] = 0u;
    if (tid == 0) lcnt = 0;
    __syncthreads();
    if (tid < B) { int c = cur[tid]; curl[tid] = c; atomicOr(&tbl[(c >> 5) & 31], 1u << (c & 31)); }
    __syncthreads();
    long base = ((long)blockIdx.x * 256 + tid) * 4;
    if (base < NE) {
        int ds4[4];
        if (base + 4 <= NE) {
            int4 d4 = *(const int4*)(ei + NE + base);
            ds4[0] = d4.x; ds4[1] = d4.y; ds4[2] = d4.z; ds4[3] = d4.w;
        } else {
            for (int k = 0; k < 4; ++k) ds4[k] = (base + k < NE) ? ei[NE + base + k] : -1;
        }
        #pragma unroll
        for (int k = 0; k < 4; ++k) {
            int dst = ds4[k];
            if (dst < 0) continue;
            if (!(tbl[(dst >> 5) & 31] & (1u << (dst & 31)))) continue;
            int e = (int)base + k;
            int r = -1, src = 0;
            for (int b = 0; b < B; ++b) {
                if (dst == curl[b]) {
                    if (r < 0) { r = et[e]; src = ei[e]; }
                    atomicAdd(&wcnt[b * R + r], 1.0f);
                    int p = atomicAdd(&lcnt, 1);
                    if (p < 64) loc[p] = int2{src, b * R + r};
                }
            }
        }
    }
    __syncthreads();
    int n = lcnt; if (n > 64) n = 64;
    for (int m = 0; m < n; ++m) {
        int2 pr = loc[m];
        const float* xs = x + (long)pr.x * D;
        float* sm = wsum + (long)pr.y * D;
        for (int t = tid; t < D; t += 256) atomicAdd(&sm[t], xs[t]);
    }
}

// RGCN transform: 72 blocks x 25-row K-chunks; last block emits hcb bf16 [32][320].
__global__ __launch_bounds__(320) void rgcn_hc(
        const float* __restrict__ x, const int* __restrict__ cur,
        const float* __restrict__ comp, const float* __restrict__ root,
        const float* __restrict__ basis, const float* __restrict__ bias,
        const float* __restrict__ wsum, const float* __restrict__ wcnt,
        float* __restrict__ hcf, int* __restrict__ done, __bf16* __restrict__ hcb) {
    int kc = blockIdx.x, t = threadIdx.x;
    __shared__ float uL[800];       // 32 b x 25 k
    __shared__ float inv[B * R];
    __shared__ float cmp[R * R];
    __shared__ int lastFlag;
    if (t < B * R) inv[t] = 1.0f / fmaxf(wcnt[t], 1.0f);
    if (t >= 160 && t < 160 + R * R) cmp[t - 160] = comp[t - 160];
    __syncthreads();
    int d0 = kc * 25;
    if (d0 < 300) {
        for (int i = t; i < 800; i += 320) {
            int b = i / 25, dd = i - b * 25;
            uL[i] = x[(long)cur[b] * D + d0 + dd];
        }
    } else {
        int g0 = d0 - 300;
        int bb = g0 / 300, t0 = g0 - bb * 300;   // 25 | 300, no straddle
        for (int i = t; i < 800; i += 320) {
            int b = i / 25, dd = i - b * 25;
            float a = 0.f;
            #pragma unroll
            for (int r = 0; r < R; ++r)
                a = fmaf(cmp[r * R + bb] * inv[b * R + r], wsum[(long)(b * R + r) * D + t0 + dd], a);
            uL[i] = a;
        }
    }
    __syncthreads();
    if (t < D) {
        const float* Mb = (d0 < 300) ? (root + (long)d0 * D) : (basis + (long)(d0 - 300) * D);
        float acc[B] = {};
        #pragma unroll 5
        for (int i = 0; i < 25; ++i) {
            float m = Mb[(long)i * D + t];
            #pragma unroll
            for (int b = 0; b < B; ++b) acc[b] = fmaf(uL[b * 25 + i], m, acc[b]);
        }
        for (int b = 0; b < B; ++b) atomicAdd(&hcf[b * D + t], acc[b]);
    }
    __syncthreads();
    if (t == 0) {
        __threadfence();
        int p = atomicAdd(done, 1);
        lastFlag = (p == 71);
    }
    __syncthreads();
    if (!lastFlag) return;
    __threadfence();
    for (int i = t; i < 32 * 320; i += 320) {
        int b = i / 320, kk = i - b * 320;
        float a = 0.f;
        if (kk < D) a = fmaxf(atomicAdd(&hcf[b * D + kk], 0.0f) + bias[kk], 0.f);
        hcb[i] = (__bf16)a;
    }
}

// Head GEMM, 16x16x32 MFMA. One wave per block, wave = 16 j-rows x ALL 32 b.
// W streamed exactly once; two MFMAs per k-step share one A-frag. ~130 VGPR,
// 3125 blocks (~12 waves/CU) -> BW-bound.
__global__ __launch_bounds__(64) void head_gemm16(
    const __bf16* __restrict__ hcb, const float* __restrict__ wg, const float* __restrict__ bg,
    const float* __restrict__ wsn, const float* __restrict__ bsn,
    float* __restrict__ out, float2* __restrict__ pm2) {
    int l = threadIdx.x;
    int jt = blockIdx.x;
    int j0 = jt * 16;
    int ln = l & 15, og = l >> 4;          // j/b-in-tile, k-octet (0..3)

    bf16x8 bfrag0[10], bfrag1[10];
    const __bf16* hrow0 = hcb + ln * 320 + og * 8;         // b = ln
    const __bf16* hrow1 = hcb + (16 + ln) * 320 + og * 8;  // b = 16 + ln
    #pragma unroll
    for (int s = 0; s < 10; ++s) {
        bfrag0[s] = *(const bf16x8*)(hrow0 + 32 * s);
        bfrag1[s] = *(const bf16x8*)(hrow1 + 32 * s);
    }

    int row = j0 + ln;
    const float* wrow = ((row < NG) ? (wg + (long)row * D) : (wsn + (long)(row - NG) * D)) + og * 8;

    f32x4 acc0 = {}, acc1 = {};
    #pragma unroll
    for (int s = 0; s < 9; ++s) {
        float4 w0 = *(const float4*)(wrow + 32 * s);
        float4 w1 = *(const float4*)(wrow + 32 * s + 4);
        bf16x8 a;
        a[0]=(__bf16)w0.x; a[1]=(__bf16)w0.y; a[2]=(__bf16)w0.z; a[3]=(__bf16)w0.w;
        a[4]=(__bf16)w1.x; a[5]=(__bf16)w1.y; a[6]=(__bf16)w1.z; a[7]=(__bf16)w1.w;
        acc0 = __builtin_amdgcn_mfma_f32_16x16x32_bf16(a, bfrag0[s], acc0, 0, 0, 0);
        acc1 = __builtin_amdgcn_mfma_f32_16x16x32_bf16(a, bfrag1[s], acc1, 0, 0, 0);
    }
    {   // tail: k = 288 + og*8 + i; og0: 288..295, og1: 296..299(+pad), og2/3: pad
        float4 w0 = float4{0.f,0.f,0.f,0.f}, w1 = float4{0.f,0.f,0.f,0.f};
        if (og == 0) { w0 = *(const float4*)(wrow + 288); w1 = *(const float4*)(wrow + 292); }
        else if (og == 1) { w0 = *(const float4*)(wrow + 288); }  // k 296..299
        bf16x8 a;
        a[0]=(__bf16)w0.x; a[1]=(__bf16)w0.y; a[2]=(__bf16)w0.z; a[3]=(__bf16)w0.w;
        a[4]=(__bf16)w1.x; a[5]=(__bf16)w1.y; a[6]=(__bf16)w1.z; a[7]=(__bf16)w1.w;
        acc0 = __builtin_amdgcn_mfma_f32_16x16x32_bf16(a, bfrag0[9], acc0, 0, 0, 0);
        acc1 = __builtin_amdgcn_mfma_f32_16x16x32_bf16(a, bfrag1[9], acc1, 0, 0, 0);
    }

    // C: col = ln -> b (acc0: ln, acc1: 16+ln), row = og*4 + r -> j
    int b0 = ln, b1 = 16 + ln;
    float m0 = -3.0e38f, s0 = 0.f, m1 = -3.0e38f, s1 = 0.f;   // acc0: glob, sense
    float m2 = -3.0e38f, s2 = 0.f, m3 = -3.0e38f, s3 = 0.f;   // acc1: glob, sense
    #pragma unroll
    for (int r = 0; r < 4; ++r) {
        int j = j0 + og * 4 + r;
        float bv = (j < NG) ? bg[j] : bsn[j - NG];
        float v0 = acc0[r] + bv;
        float v1 = acc1[r] + bv;
        float* op0 = (j < NG) ? (out + (long)b0 * NG + j)
                              : (out + (long)B * NG + (long)b0 * NS + (j - NG));
        float* op1 = (j < NG) ? (out + (long)b1 * NG + j)
                              : (out + (long)B * NG + (long)b1 * NS + (j - NG));
        *op0 = v0;
        *op1 = v1;
        if (j < NG) { online_upd(m0, s0, v0); online_upd(m2, s2, v1); }
        else        { online_upd(m1, s1, v0); online_upd(m3, s3, v1); }
    }
    // merge the 4 lanes sharing ln (og 0..3): xor 16, then xor 32
    #pragma unroll
    for (int o = 16; o <= 32; o <<= 1) {
        float t;
        t = __shfl_xor(m0, o); { float ts = __shfl_xor(s0, o); online_merge(m0, s0, t, ts); }
        t = __shfl_xor(m1, o); { float ts = __shfl_xor(s1, o); online_merge(m1, s1, t, ts); }
        t = __shfl_xor(m2, o); { float ts = __shfl_xor(s2, o); online_merge(m2, s2, t, ts); }
        t = __shfl_xor(m3, o); { float ts = __shfl_xor(s3, o); online_merge(m3, s3, t, ts); }
    }
    if (og == 0) {
        pm2[(long)b0 * NT16 + jt]       = float2{m0, s0};
        pm2[(long)(B + b0) * NT16 + jt] = float2{m1, s1};
        pm2[(long)b1 * NT16 + jt]       = float2{m2, s2};
        pm2[(long)(B + b1) * NT16 + jt] = float2{m3, s3};
    }
}

// One block per output row: reduce its 3125-tile strip -> lse[row].
__global__ __launch_bounds__(256) void lse_red(const float2* __restrict__ pm2,
                                               float* __restrict__ lse) {
    int rw = blockIdx.x, tid = threadIdx.x;
    const float2* pr = pm2 + (long)rw * NT16;
    float m = -3.0e38f, s = 0.f;
    for (int i = tid; i < NT16; i += 256) { float2 e = pr[i]; online_merge(m, s, e.x, e.y); }
    #pragma unroll
    for (int o = 32; o; o >>= 1) {
        float om = __shfl_xor(m, o), os = __shfl_xor(s, o);
        online_merge(m, s, om, os);
    }
    __shared__ float sm[4], ss[4];
    if ((tid & 63) == 0) { sm[tid >> 6] = m; ss[tid >> 6] = s; }
    __syncthreads();
    if (tid == 0) {
        float M = sm[0], S = ss[0];
        for (int w = 1; w < 4; ++w) online_merge(M, S, sm[w], ss[w]);
        lse[rw] = M + __logf(S);
    }
}

// 1600 blocks: subtract lse over 250-float4 chunks.
__global__ __launch_bounds__(256) void sub_lse(float* __restrict__ out,
                                               const float* __restrict__ lse) {
    int rw = blockIdx.x / 25, c = blockIdx.x % 25;
    float l = lse[rw];
    float4* o4 = (float4*)out + (long)rw * 6250 + c * 250;
    int tid = threadIdx.x;
    if (tid < 250) { float4 v = o4[tid]; v.x -= l; v.y -= l; v.z -= l; v.w -= l; o4[tid] = v; }
}

extern "C" void kernel_launch(void* const* d_in, const int* in_sizes, int n_in,
                              void* d_out, int out_size, void* d_ws, size_t ws_size,
                              hipStream_t stream) {
    const float* x     = (const float*)d_in[0];
    const int*   ei    = (const int*)d_in[1];
    const int*   et    = (const int*)d_in[2];
    const int*   cur   = (const int*)d_in[3];
    const float* basis = (const float*)d_in[4];
    const float* comp  = (const float*)d_in[5];
    const float* root  = (const float*)d_in[6];
    const float* bias  = (const float*)d_in[7];
    const float* wg    = (const float*)d_in[8];
    const float* bgl   = (const float*)d_in[9];
    const float* wsn   = (const float*)d_in[10];
    const float* bsn   = (const float*)d_in[11];
    float* out  = (float*)d_out;
    float* wsf  = (float*)d_ws;
    float*  wsum = wsf;                        // [0, 48000)
    float*  wcnt = wsf + 48000;                // [48000, 48160)
    float*  hcf  = wsf + 48160;                // [48160, 57760)
    int*    done = (int*)(wsf + 57760);
    __bf16* hcb  = (__bf16*)(wsf + 57764);     // 32 x 320 bf16
    float2* pm2  = (float2*)(wsf + 62884);     // 64 x 3125
    float*  lse  = wsf + 462884;               // 64

    zero_ws<<<57, 256, 0, stream>>>((float4*)d_ws);
    scan_accum<<<977, 256, 0, stream>>>(ei, et, cur, x, wsum, wcnt);
    rgcn_hc<<<72, 320, 0, stream>>>(x, cur, comp, root, basis, bias, wsum, wcnt, hcf, done, hcb);
    head_gemm16<<<NT16, 64, 0, stream>>>(hcb, wg, bgl, wsn, bsn, out, pm2);
    lse_red<<<64, 256, 0, stream>>>(pm2, lse);
    sub_lse<<<1600, 256, 0, stream>>>(out, lse);
}